// Round 3
// baseline (6319.542 us; speedup 1.0000x reference)
//
#include <hip/hip_runtime.h>
#include <hip/hip_bf16.h>

#define NN 100000
#define EE 3200000
#define HD 64
#define NF 512
#define NC 256

#define BSH 7                 // 128 nodes per bucket
#define BNODES 128
#define NBUK 782              // ceil(100000/128)
#define BCAP 4800             // bucket capacity (mean 4096, sigma 64 -> +11 sigma), mult of 16
#define PCHUNK 8192           // edges per partition block
#define PBLK ((EE + PCHUNK - 1) / PCHUNK)   // 391

// ---------------- bucket partition ----------------

__global__ __launch_bounds__(256) void init_cursor(int* __restrict__ cursor) {
    int b = blockIdx.x * 256 + threadIdx.x;
    if (b < NBUK) cursor[b] = b * BCAP;
}

__global__ __launch_bounds__(256) void partition_edges(const int* __restrict__ src, const int* __restrict__ dst,
                                                       int* __restrict__ cursor, unsigned int* __restrict__ packed) {
    __shared__ int hist[NBUK];
    __shared__ int gbase[NBUK];
    __shared__ int lcur[NBUK];
    int tid = threadIdx.x;
    for (int i = tid; i < NBUK; i += 256) hist[i] = 0;
    __syncthreads();
    int e0 = blockIdx.x * PCHUNK;
#pragma unroll
    for (int i = 0; i < PCHUNK / 256; ++i) {
        int e = e0 + i * 256 + tid;
        if (e < EE) atomicAdd(&hist[dst[e] >> BSH], 1);
    }
    __syncthreads();
    for (int i = tid; i < NBUK; i += 256) {
        int hh = hist[i];
        gbase[i] = hh ? atomicAdd(&cursor[i], hh) : 0;
        lcur[i] = 0;
    }
    __syncthreads();
#pragma unroll
    for (int i = 0; i < PCHUNK / 256; ++i) {
        int e = e0 + i * 256 + tid;
        if (e < EE) {
            int d = dst[e], s = src[e];
            int bk = d >> BSH;
            int loc = atomicAdd(&lcur[bk], 1);
            int pos = gbase[bk] + loc;
            if (pos < (bk + 1) * BCAP)  // overflow guard (statistically impossible)
                packed[pos] = ((unsigned int)s << 8) | (unsigned int)(d & (BNODES - 1));
        }
    }
}

// pad each bucket to a multiple of 16 edges with sentinels (row 128 = trash row)
__global__ __launch_bounds__(256) void pad_buckets(int* __restrict__ cursor, unsigned int* __restrict__ packed,
                                                   int* __restrict__ blen) {
    int b = blockIdx.x * 256 + threadIdx.x;
    if (b >= NBUK) return;
    int c = cursor[b] - b * BCAP;
    if (c > BCAP) c = BCAP;
    int plen = (c + 15) & ~15;
    for (int i = c; i < plen; ++i) packed[b * BCAP + i] = 128u;  // src=0, row=128 (trash)
    blen[b] = plen;
}

// ---------------- GEMM: h = x @ Win + b_in  [100000,512]x[512,64] ----------------

__global__ __launch_bounds__(256) void gemm_in(const float* __restrict__ x, const float* __restrict__ Win,
                                               const float* __restrict__ b_in, float* __restrict__ h) {
    __shared__ float xs[64 * 64];  // 16 KB
    int tid = threadIdx.x;
    int lane = tid & 63, wave = tid >> 6;
    int rowBase = blockIdx.x * 64;
    float bb = b_in[lane];
    float acc[16];
#pragma unroll
    for (int r = 0; r < 16; ++r) acc[r] = bb;

    for (int kt = 0; kt < NF; kt += 64) {
        __syncthreads();
#pragma unroll
        for (int i = 0; i < 4; ++i) {
            int idx = tid + 256 * i;
            int r = idx >> 4;
            int c4 = idx & 15;
            int grow = rowBase + r;
            if (grow >= NN) grow = NN - 1;
            float4 v = *(const float4*)(x + (size_t)grow * NF + kt + c4 * 4);
            *(float4*)(xs + r * 64 + c4 * 4) = v;
        }
        __syncthreads();
        const float* wsrc = Win + (size_t)kt * HD;
        for (int k = 0; k < 64; k += 4) {
            float w0 = wsrc[(k + 0) * HD + lane];
            float w1 = wsrc[(k + 1) * HD + lane];
            float w2 = wsrc[(k + 2) * HD + lane];
            float w3 = wsrc[(k + 3) * HD + lane];
#pragma unroll
            for (int r = 0; r < 16; ++r) {
                float4 xv = *(const float4*)(xs + (wave * 16 + r) * 64 + k);
                acc[r] = fmaf(xv.x, w0, acc[r]);
                acc[r] = fmaf(xv.y, w1, acc[r]);
                acc[r] = fmaf(xv.z, w2, acc[r]);
                acc[r] = fmaf(xv.w, w3, acc[r]);
            }
        }
    }
#pragma unroll
    for (int r = 0; r < 16; ++r) {
        int row = rowBase + wave * 16 + r;
        if (row < NN) h[(size_t)row * HD + lane] = acc[r];
    }
}

// ---------------- Aggregation: bucket-local LDS accumulation ----------------
// one block per bucket; wave streams 8 edges: coalesced 256B h-row load + ds_add_f32.

__global__ __launch_bounds__(256) void aggregate(const float* __restrict__ h, const unsigned int* __restrict__ packed,
                                                 const int* __restrict__ blen, float4* __restrict__ agg4) {
    __shared__ float accum[129 * 64];  // 128 real rows + 1 trash row
    __shared__ int cntl[129];
    int tid = threadIdx.x;
    int b = blockIdx.x;
    for (int i = tid; i < 129 * 64; i += 256) accum[i] = 0.f;
    if (tid < 129) cntl[tid] = 0;
    __syncthreads();

    int lane = tid & 63;
    int wv = __builtin_amdgcn_readfirstlane(tid >> 6);
    int base = b * BCAP;
    int len = blen[b];

    for (int e = wv * 8; e < len; e += 32) {
        unsigned int p[8];
#pragma unroll
        for (int j = 0; j < 8; ++j) p[j] = packed[base + e + j];
#pragma unroll
        for (int j = 0; j < 8; ++j) {
            int s = (int)(p[j] >> 8);
            int row = (int)(p[j] & 255u);
            float v = h[(size_t)s * HD + lane];
            atomicAdd(&accum[row * 64 + lane], v);
            if (lane == 0) atomicAdd(&cntl[row], 1);
        }
    }
    __syncthreads();

    int nodeBase = b << BSH;
    for (int i = tid; i < BNODES * 16; i += 256) {
        int row = i >> 4, c4 = i & 15;
        int node = nodeBase + row;
        if (node < NN) {
            int c = cntl[row];
            float s = 1.0f / (float)(c > 1 ? c : 1);
            float4 r;
            r.x = accum[row * 64 + c4 * 4 + 0] * s;
            r.y = accum[row * 64 + c4 * 4 + 1] * s;
            r.z = accum[row * 64 + c4 * 4 + 2] * s;
            r.w = accum[row * 64 + c4 * 4 + 3] * s;
            agg4[(size_t)node * 16 + c4] = r;
        }
    }
}

// ---------------- Layer: h = h + relu(agg@Wl + bl + h@Wr) ----------------

__global__ __launch_bounds__(256) void layer_conv(const float* __restrict__ agg, float* __restrict__ h,
                                                  const float* __restrict__ Wl, const float* __restrict__ Wr,
                                                  const float* __restrict__ bl) {
    __shared__ float as_[64 * 64];
    __shared__ float hs[64 * 64];
    int tid = threadIdx.x;
    int lane = tid & 63, wave = tid >> 6;
    int rowBase = blockIdx.x * 64;
    float bb = bl[lane];
    float acc[16];
#pragma unroll
    for (int r = 0; r < 16; ++r) acc[r] = bb;

#pragma unroll
    for (int i = 0; i < 4; ++i) {
        int idx = tid + 256 * i;
        int r = idx >> 4;
        int c4 = idx & 15;
        int grow = rowBase + r;
        if (grow >= NN) grow = NN - 1;
        *(float4*)(as_ + r * 64 + c4 * 4) = *(const float4*)(agg + (size_t)grow * HD + c4 * 4);
        *(float4*)(hs + r * 64 + c4 * 4) = *(const float4*)(h + (size_t)grow * HD + c4 * 4);
    }
    __syncthreads();

    for (int k = 0; k < 64; k += 4) {
        float wl0 = Wl[(k + 0) * HD + lane];
        float wl1 = Wl[(k + 1) * HD + lane];
        float wl2 = Wl[(k + 2) * HD + lane];
        float wl3 = Wl[(k + 3) * HD + lane];
        float wr0 = Wr[(k + 0) * HD + lane];
        float wr1 = Wr[(k + 1) * HD + lane];
        float wr2 = Wr[(k + 2) * HD + lane];
        float wr3 = Wr[(k + 3) * HD + lane];
#pragma unroll
        for (int r = 0; r < 16; ++r) {
            float4 av = *(const float4*)(as_ + (wave * 16 + r) * 64 + k);
            float4 hv = *(const float4*)(hs + (wave * 16 + r) * 64 + k);
            acc[r] = fmaf(av.x, wl0, acc[r]);
            acc[r] = fmaf(av.y, wl1, acc[r]);
            acc[r] = fmaf(av.z, wl2, acc[r]);
            acc[r] = fmaf(av.w, wl3, acc[r]);
            acc[r] = fmaf(hv.x, wr0, acc[r]);
            acc[r] = fmaf(hv.y, wr1, acc[r]);
            acc[r] = fmaf(hv.z, wr2, acc[r]);
            acc[r] = fmaf(hv.w, wr3, acc[r]);
        }
    }
#pragma unroll
    for (int r = 0; r < 16; ++r) {
        int row = rowBase + wave * 16 + r;
        if (row < NN) {
            float ho = hs[(wave * 16 + r) * 64 + lane];
            float c = acc[r];
            h[(size_t)row * HD + lane] = ho + (c > 0.f ? c : 0.f);
        }
    }
}

// ---------------- Output GEMM: out = h @ Wout + b_out ----------------

__global__ __launch_bounds__(256) void gemm_out_k(const float* __restrict__ h, const float* __restrict__ Wout,
                                                  const float* __restrict__ b_out, float* __restrict__ out) {
    __shared__ float hs[32 * 64];
    int tid = threadIdx.x;
    int rowBase = blockIdx.x * 32;
#pragma unroll
    for (int i = 0; i < 2; ++i) {
        int idx = tid + 256 * i;
        int r = idx >> 4;
        int c4 = idx & 15;
        int grow = rowBase + r;
        if (grow >= NN) grow = NN - 1;
        *(float4*)(hs + r * 64 + c4 * 4) = *(const float4*)(h + (size_t)grow * HD + c4 * 4);
    }
    __syncthreads();

    int j = tid;
    float bb = b_out[j];
    float acc[32];
#pragma unroll
    for (int r = 0; r < 32; ++r) acc[r] = bb;

    for (int k = 0; k < 64; k += 4) {
        float w0 = Wout[(k + 0) * NC + j];
        float w1 = Wout[(k + 1) * NC + j];
        float w2 = Wout[(k + 2) * NC + j];
        float w3 = Wout[(k + 3) * NC + j];
#pragma unroll
        for (int r = 0; r < 32; ++r) {
            float4 hv = *(const float4*)(hs + r * 64 + k);
            acc[r] = fmaf(hv.x, w0, acc[r]);
            acc[r] = fmaf(hv.y, w1, acc[r]);
            acc[r] = fmaf(hv.z, w2, acc[r]);
            acc[r] = fmaf(hv.w, w3, acc[r]);
        }
    }
#pragma unroll
    for (int r = 0; r < 32; ++r) {
        int row = rowBase + r;
        if (row < NN) out[(size_t)row * NC + j] = acc[r];
    }
}

extern "C" void kernel_launch(void* const* d_in, const int* in_sizes, int n_in,
                              void* d_out, int out_size, void* d_ws, size_t ws_size,
                              hipStream_t stream) {
    const float* x    = (const float*)d_in[0];
    const int*   ei   = (const int*)d_in[1];   // [2, E]: src then dst
    const float* Win  = (const float*)d_in[2];
    const float* b_in = (const float*)d_in[3];
    const float* Wl   = (const float*)d_in[4];
    const float* bl   = (const float*)d_in[5];
    const float* Wr   = (const float*)d_in[6];
    const float* Wout = (const float*)d_in[7];
    const float* b_out= (const float*)d_in[8];
    float* out = (float*)d_out;

    const int* src = ei;
    const int* dst = ei + EE;

    char* ws = (char*)d_ws;
    float* h      = (float*)ws;                                  // 25.6 MB
    float* agg    = h + (size_t)NN * HD;                         // 25.6 MB
    unsigned int* packed = (unsigned int*)(agg + (size_t)NN * HD); // NBUK*BCAP u32 = 15.0 MB
    int*   cursor = (int*)(packed + (size_t)NBUK * BCAP);        // 782
    int*   blen   = cursor + NBUK;                               // 782

    init_cursor<<<(NBUK + 255) / 256, 256, 0, stream>>>(cursor);
    partition_edges<<<PBLK, 256, 0, stream>>>(src, dst, cursor, packed);
    pad_buckets<<<(NBUK + 255) / 256, 256, 0, stream>>>(cursor, packed, blen);

    gemm_in<<<(NN + 63) / 64, 256, 0, stream>>>(x, Win, b_in, h);

    for (int i = 0; i < 4; ++i) {
        aggregate<<<NBUK, 256, 0, stream>>>(h, packed, blen, (float4*)agg);
        layer_conv<<<(NN + 63) / 64, 256, 0, stream>>>(agg, h, Wl + (size_t)i * HD * HD,
                                                       Wr + (size_t)i * HD * HD, bl + (size_t)i * HD);
    }

    gemm_out_k<<<(NN + 31) / 32, 256, 0, stream>>>(h, Wout, b_out, out);
}